// Round 16
// baseline (88.299 us; speedup 1.0000x reference)
//
#include <hip/hip_runtime.h>
#include <hip/hip_cooperative_groups.h>

namespace cg = cooperative_groups;

constexpr int N_NODES  = 4000000;
constexpr int N_GRAPHS = 4096;
constexpr int D_FEAT   = 8;
constexpr int N_CLS    = 10;
constexpr int NBLK     = 1024;            // 4 blocks/CU, co-resident
constexpr int NTHREADS = 256;

typedef float f32x4 __attribute__((ext_vector_type(4)));
typedef int   i32x4 __attribute__((ext_vector_type(4)));

// Single cooperative dispatch.
// Phase A: grid-stride linear boundary scan of ids (16 MB, coalesced, the
//          mandatory bytes; no search, no probe overfetch) -> bounds[4097].
// grid.sync()
// Phase B: wave (blockIdx*4+wid) == graph g: two L2-hot bounds taps, then
//          unpredicated ILP-4 unit-stride float4 stream over x[s:e),
//          parity-split butterfly, direct 10-logit write. No atomics.
__global__ __launch_bounds__(256) void fused_coop(
    const float* __restrict__ x,       // [N_NODES, 8]
    const int*   __restrict__ ids,     // [N_NODES] sorted
    const float* __restrict__ W,       // [N_CLS, D_FEAT]
    const float* __restrict__ bias,    // [N_CLS]
    float*       __restrict__ out,     // [N_GRAPHS, N_CLS]
    int*         __restrict__ bounds)  // [N_GRAPHS+1] workspace
{
    const f32x4* xf   = (const f32x4*)x;
    const i32x4* ids4 = (const i32x4*)ids;
    int tid  = blockIdx.x * blockDim.x + threadIdx.x;
    int nthr = NBLK * NTHREADS;        // 262144 threads, 4 ids each per pass

    // ---- Phase A: boundary scan (bounds[g] = first i with ids[i] >= g) ----
    for (int t = tid; t < N_NODES / 4; t += nthr) {
        int base = t * 4;
        i32x4 v = ids4[t];
        int prev = (base == 0) ? -1 : ids[base - 1];   // neighbor line: cache hit
        int cur;
        cur = v.x; if (cur != prev) { for (int g = prev + 1; g <= cur; ++g) bounds[g] = base + 0; } prev = cur;
        cur = v.y; if (cur != prev) { for (int g = prev + 1; g <= cur; ++g) bounds[g] = base + 1; } prev = cur;
        cur = v.z; if (cur != prev) { for (int g = prev + 1; g <= cur; ++g) bounds[g] = base + 2; } prev = cur;
        cur = v.w; if (cur != prev) { for (int g = prev + 1; g <= cur; ++g) bounds[g] = base + 3; } prev = cur;
        if (base + 4 >= N_NODES) {                     // close the tail
            for (int g = prev + 1; g <= N_GRAPHS; ++g) bounds[g] = N_NODES;
        }
    }

    cg::this_grid().sync();            // device-scope fence + grid barrier

    // ---- Phase B: one graph per wave ----
    int wid  = threadIdx.x >> 6;
    int lane = threadIdx.x & 63;
    int g    = blockIdx.x * 4 + wid;   // 1024 blocks * 4 waves = 4096 graphs

    int s = bounds[g];                 // wave-uniform scalar taps (L2-hot)
    int e = bounds[g + 1];

    // Unit-stride float4 stream; lane parity fixes its feature half
    // (even lanes: feats 0-3, odd: feats 4-7). Unpredicated ILP-4 body.
    f32x4 a0 = (f32x4)(0.f), a1 = (f32x4)(0.f),
          a2 = (f32x4)(0.f), a3 = (f32x4)(0.f);
    int i    = 2 * s + lane;
    int endf = 2 * e;
    int full = (endf - 2 * s) >> 8;    // full 256-f4 rounds
    for (int it = 0; it < full; ++it, i += 256) {
        a0 += xf[i];
        a1 += xf[i +  64];
        a2 += xf[i + 128];
        a3 += xf[i + 192];
    }
    for (; i < endf; i += 64) a0 += xf[i];   // exec-masked tail
    f32x4 acc = (a0 + a1) + (a2 + a3);

    // Butterfly over even offsets: lane 0 ends with feats 0-3 totals,
    // lane 1 with feats 4-7 totals.
    #pragma unroll
    for (int off = 32; off >= 2; off >>= 1) {
        acc.x += __shfl_xor(acc.x, off);
        acc.y += __shfl_xor(acc.y, off);
        acc.z += __shfl_xor(acc.z, off);
        acc.w += __shfl_xor(acc.w, off);
    }
    // Broadcast the 8 sums to all lanes.
    float m0 = __shfl(acc.x, 0), m1 = __shfl(acc.y, 0);
    float m2 = __shfl(acc.z, 0), m3 = __shfl(acc.w, 0);
    float m4 = __shfl(acc.x, 1), m5 = __shfl(acc.y, 1);
    float m6 = __shfl(acc.z, 1), m7 = __shfl(acc.w, 1);

    if (lane < N_CLS) {
        float inv = 1.0f / (float)(e - s);
        const float* w = W + (size_t)lane * D_FEAT;
        float a = bias[lane];
        a += (m0 * inv) * w[0] + (m1 * inv) * w[1]
           + (m2 * inv) * w[2] + (m3 * inv) * w[3]
           + (m4 * inv) * w[4] + (m5 * inv) * w[5]
           + (m6 * inv) * w[6] + (m7 * inv) * w[7];
        out[(size_t)g * N_CLS + lane] = a;
    }
}

extern "C" void kernel_launch(void* const* d_in, const int* in_sizes, int n_in,
                              void* d_out, int out_size, void* d_ws, size_t ws_size,
                              hipStream_t stream) {
    const float* x   = (const float*)d_in[0];   // [4M, 8] f32
    const int*   ids = (const int*)d_in[1];     // [4M] sorted segment ids
    // d_in[2] input_ids, d_in[3] attention_mask: unused by the forward
    const float* W   = (const float*)d_in[4];   // [10, 8]
    const float* b   = (const float*)d_in[5];   // [10]
    float*       out = (float*)d_out;           // [4096, 10]
    int*         bounds = (int*)d_ws;           // [N_GRAPHS+1]

    void* args[] = { (void*)&x, (void*)&ids, (void*)&W, (void*)&b,
                     (void*)&out, (void*)&bounds };
    hipLaunchCooperativeKernel((const void*)fused_coop,
                               dim3(NBLK), dim3(NTHREADS),
                               args, 0, stream);
}

// Round 17
// 29.898 us; speedup vs baseline: 2.9534x; 2.9534x over previous
//
#include <hip/hip_runtime.h>

constexpr int N_NODES  = 4000000;
constexpr int N_GRAPHS = 4096;
constexpr int D_FEAT   = 8;
constexpr int N_CLS    = 10;

typedef float f32x4 __attribute__((ext_vector_type(4)));
typedef int   i32x4 __attribute__((ext_vector_type(4)));

// K1: bandwidth-parallel linear boundary scan of ids (16 MB coalesced — the
// mandatory bytes; no search, no probe overfetch). bounds[g] = lower_bound(g).
__global__ __launch_bounds__(256) void scan_bounds(
    const i32x4* __restrict__ ids4, const int* __restrict__ ids,
    int* __restrict__ bounds)
{
    int t = blockIdx.x * blockDim.x + threadIdx.x;
    int base = t * 4;
    if (base >= N_NODES) return;

    i32x4 v = ids4[t];
    int prev = (base == 0) ? -1 : ids[base - 1];   // neighbor's line: cache hit

    int cur;
    cur = v.x; if (cur != prev) { for (int g = prev + 1; g <= cur; ++g) bounds[g] = base + 0; } prev = cur;
    cur = v.y; if (cur != prev) { for (int g = prev + 1; g <= cur; ++g) bounds[g] = base + 1; } prev = cur;
    cur = v.z; if (cur != prev) { for (int g = prev + 1; g <= cur; ++g) bounds[g] = base + 2; } prev = cur;
    cur = v.w; if (cur != prev) { for (int g = prev + 1; g <= cur; ++g) bounds[g] = base + 3; } prev = cur;

    if (base + 4 >= N_NODES) {                     // close the tail
        for (int g = prev + 1; g <= N_GRAPHS; ++g) bounds[g] = N_NODES;
    }
}

// K2: one wave per graph. Two wave-uniform bounds taps (L2-hot), then an
// unpredicated ILP-4 unit-stride float4 stream over x[s:e), parity-split
// butterfly, direct 10-logit write. No search, no atomics.
__global__ __launch_bounds__(256) void pool_linear(
    const float* __restrict__ x,       // [N_NODES, 8]
    const int*   __restrict__ bounds,  // [N_GRAPHS+1]
    const float* __restrict__ W,       // [N_CLS, D_FEAT]
    const float* __restrict__ bias,    // [N_CLS]
    float*       __restrict__ out)     // [N_GRAPHS, N_CLS]
{
    const f32x4* xf = (const f32x4*)x; // [N_NODES*2] flat float4 view
    int wid  = threadIdx.x >> 6;
    int lane = threadIdx.x & 63;
    int g    = blockIdx.x * 4 + wid;   // 1024 blocks * 4 waves = 4096 graphs

    int s = bounds[g];
    int e = bounds[g + 1];

    // Unit-stride float4 stream; lane parity fixes its feature half
    // (even lanes: feats 0-3, odd: feats 4-7). Unpredicated ILP-4 body.
    f32x4 a0 = (f32x4)(0.f), a1 = (f32x4)(0.f),
          a2 = (f32x4)(0.f), a3 = (f32x4)(0.f);
    int i    = 2 * s + lane;
    int endf = 2 * e;
    int full = (endf - 2 * s) >> 8;    // full 256-f4 rounds
    for (int it = 0; it < full; ++it, i += 256) {
        a0 += xf[i];
        a1 += xf[i +  64];
        a2 += xf[i + 128];
        a3 += xf[i + 192];
    }
    for (; i < endf; i += 64) a0 += xf[i];   // exec-masked tail
    f32x4 acc = (a0 + a1) + (a2 + a3);

    // Butterfly over even offsets: lane 0 ends with feats 0-3 totals,
    // lane 1 with feats 4-7 totals.
    #pragma unroll
    for (int off = 32; off >= 2; off >>= 1) {
        acc.x += __shfl_xor(acc.x, off);
        acc.y += __shfl_xor(acc.y, off);
        acc.z += __shfl_xor(acc.z, off);
        acc.w += __shfl_xor(acc.w, off);
    }
    // Broadcast the 8 sums to all lanes.
    float m0 = __shfl(acc.x, 0), m1 = __shfl(acc.y, 0);
    float m2 = __shfl(acc.z, 0), m3 = __shfl(acc.w, 0);
    float m4 = __shfl(acc.x, 1), m5 = __shfl(acc.y, 1);
    float m6 = __shfl(acc.z, 1), m7 = __shfl(acc.w, 1);

    if (lane < N_CLS) {
        float inv = 1.0f / (float)(e - s);
        const float* w = W + (size_t)lane * D_FEAT;
        float a = bias[lane];
        a += (m0 * inv) * w[0] + (m1 * inv) * w[1]
           + (m2 * inv) * w[2] + (m3 * inv) * w[3]
           + (m4 * inv) * w[4] + (m5 * inv) * w[5]
           + (m6 * inv) * w[6] + (m7 * inv) * w[7];
        out[(size_t)g * N_CLS + lane] = a;
    }
}

extern "C" void kernel_launch(void* const* d_in, const int* in_sizes, int n_in,
                              void* d_out, int out_size, void* d_ws, size_t ws_size,
                              hipStream_t stream) {
    const float* x   = (const float*)d_in[0];   // [4M, 8] f32
    const int*   ids = (const int*)d_in[1];     // [4M] sorted segment ids
    // d_in[2] input_ids, d_in[3] attention_mask: unused by the forward
    const float* W   = (const float*)d_in[4];   // [10, 8]
    const float* b   = (const float*)d_in[5];   // [10]
    float*       out = (float*)d_out;           // [4096, 10]

    int* bounds = (int*)d_ws;                   // [N_GRAPHS+1]

    int scan_blocks = (N_NODES / 4 + 255) / 256;          // 3907
    scan_bounds<<<scan_blocks, 256, 0, stream>>>(
        (const i32x4*)ids, ids, bounds);

    pool_linear<<<N_GRAPHS / 4, 256, 0, stream>>>(
        x, bounds, W, b, out);
}